// Round 1
// 370.677 us; speedup vs baseline: 1.0455x; 1.0455x over previous
//
#include <hip/hip_runtime.h>
#include <stdint.h>

// Problem constants
#define HH 32
#define WW 32
#define CC 512
#define CLS 1000
#define RR 64
#define BB 128
#define KK 1024            // W*H
#define MM (BB*CC)         // 65536 rows of x_flat

#define KSPLIT 4
#define KS (KK/KSPLIT)     // 256 k per block
#define QS (KS/32)         // 8 mfma k-chunks per block

typedef __bf16  bf16x8 __attribute__((ext_vector_type(8)));
typedef float   f32x4  __attribute__((ext_vector_type(4)));

// ---------------------------------------------------------------------------
// Fused main: per-block V-fragment prep (V[k,r] = U2[w,r]*U1[h,r]) into LDS,
// then t3p[b,slot,r] = sum_{c in block rows} U3[c,r] * sum_{k in slice} x*V.
// grid (MM/64, KSPLIT), block 256 (4 waves). Wave w owns rows 16w..16w+15.
// A loaded straight from global in fragment layout (nontemporal, no reuse),
// B fragments ds_read from the block-computed LDS slice.
// Partial-slot writes replace atomics -> no memset dispatch, no contention;
// every t3p element is written before out_k reads it (workspace-poison-proof).
// ---------------------------------------------------------------------------
__global__ void __launch_bounds__(256, 4)
main_k(const float* __restrict__ x, const float* __restrict__ U1,
       const float* __restrict__ U2, const float* __restrict__ U3,
       float* __restrict__ t3p) {
    __shared__ alignas(16) __bf16 vs[QS * 4 * 64 * 8];   // 32 KB
    __shared__ float red[4][64];

    const int tid = threadIdx.x;
    const int k0  = blockIdx.y * KS;

    // In-block V prep in MFMA B-fragment order:
    // vs[((q*4+f)*64 + lane)*8 + j] = V[k0 + 32q + (lane>>4)*8 + j][16f + (lane&15)]
    // Per idx: one U2 scalar (w constant over j) + 8 U1 scalars, all L1-resident.
#pragma unroll
    for (int i = 0; i < 8; ++i) {
        int idx = tid + i * 256;          // 0..2047
        int l  = idx & 63;
        int qf = idx >> 6;
        int f  = qf & 3;
        int q  = qf >> 2;
        int n  = f * 16 + (l & 15);
        int kb = k0 + q * 32 + ((l >> 4) << 3);
        int w  = kb >> 5;                  // constant across j (kb%32 in {0,8,16,24})
        int hb = kb & 31;
        float u2 = U2[w * RR + n];
        bf16x8 vv;
#pragma unroll
        for (int j = 0; j < 8; ++j)
            vv[j] = (__bf16)(u2 * U1[(hb + j) * RR + n]);
        ((bf16x8*)vs)[idx] = vv;
    }
    __syncthreads();

    const int wv = tid >> 6;
    const int l  = tid & 63;
    const int m  = blockIdx.x * 64 + wv * 16 + (l & 15);   // global row (b*512+c)
    const float* xp = x + (size_t)m * KK + k0 + ((l >> 4) * 8);

    f32x4 acc[4] = {};

#pragma unroll
    for (int q = 0; q < QS; ++q) {
        f32x4 a0 = __builtin_nontemporal_load((const f32x4*)(xp + q * 32));
        f32x4 a1 = __builtin_nontemporal_load((const f32x4*)(xp + q * 32 + 4));
        bf16x8 af;
        af[0] = (__bf16)a0.x; af[1] = (__bf16)a0.y;
        af[2] = (__bf16)a0.z; af[3] = (__bf16)a0.w;
        af[4] = (__bf16)a1.x; af[5] = (__bf16)a1.y;
        af[6] = (__bf16)a1.z; af[7] = (__bf16)a1.w;
#pragma unroll
        for (int f = 0; f < 4; ++f) {
            bf16x8 bf = ((const bf16x8*)vs)[(q * 4 + f) * 64 + l];
            acc[f] = __builtin_amdgcn_mfma_f32_16x16x32_bf16(af, bf, acc[f], 0, 0, 0);
        }
    }

    // Epilogue: weight by U3[c,r], reduce the wave's 16 rows, then the 4 waves,
    // one plain store per (b,slot,r).
    const int b      = blockIdx.x >> 3;                    // 64 rows/block, 512 c/b
    const int c_base = (blockIdx.x * 64) & (CC - 1);
    const int c_l    = c_base + wv * 16 + (l >> 4) * 4;

    float p[4];
#pragma unroll
    for (int f = 0; f < 4; ++f) {
        int r = f * 16 + (l & 15);
        float s = 0.f;
#pragma unroll
        for (int i = 0; i < 4; ++i)
            s += acc[f][i] * U3[(c_l + i) * RR + r];
        p[f] = s;
    }
#pragma unroll
    for (int f = 0; f < 4; ++f) {
        p[f] += __shfl_xor(p[f], 16, 64);
        p[f] += __shfl_xor(p[f], 32, 64);
    }
    if (l < 16) {
#pragma unroll
        for (int f = 0; f < 4; ++f) red[wv][f * 16 + l] = p[f];
    }
    __syncthreads();
    if (tid < 64) {
        float s = red[0][tid] + red[1][tid] + red[2][tid] + red[3][tid];
        int slot = ((blockIdx.x & 7) << 2) | blockIdx.y;   // 0..31 within b
        t3p[((size_t)b * 32 + slot) * RR + tid] = s;
    }
}

// ---------------------------------------------------------------------------
// Final: reduce the 32 partial slots -> t3[b,r], scale by lam, expand classes.
// out[b,cls] = sum_r (t3[b,r]*lam[r]) * U4[cls,r].  grid (4, BB), block 256.
// ---------------------------------------------------------------------------
__global__ void __launch_bounds__(256)
out_k(const float* __restrict__ t3p, const float* __restrict__ lam,
      const float* __restrict__ U4, float* __restrict__ out) {
    __shared__ float pr[4][RR];
    __shared__ float sl[RR];
    const int b   = blockIdx.y;
    const int tid = threadIdx.x;
    const int r   = tid & 63, g = tid >> 6;

    float s = 0.f;
#pragma unroll
    for (int i = 0; i < 8; ++i)
        s += t3p[((size_t)b * 32 + g * 8 + i) * RR + r];
    pr[g][r] = s;
    __syncthreads();
    if (tid < RR)
        sl[tid] = (pr[0][tid] + pr[1][tid] + pr[2][tid] + pr[3][tid]) * lam[tid];
    __syncthreads();

    const int cls = blockIdx.x * 256 + tid;
    if (cls < CLS) {
        const f32x4* u4 = (const f32x4*)(U4 + (size_t)cls * RR);
        float sacc = 0.f;
#pragma unroll
        for (int i = 0; i < 16; ++i) {
            f32x4 v = u4[i];
            sacc += v.x * sl[i*4+0] + v.y * sl[i*4+1] + v.z * sl[i*4+2] + v.w * sl[i*4+3];
        }
        out[b * CLS + cls] = sacc;
    }
}

// ---------------------------------------------------------------------------
extern "C" void kernel_launch(void* const* d_in, const int* in_sizes, int n_in,
                              void* d_out, int out_size, void* d_ws, size_t ws_size,
                              hipStream_t stream) {
    const float* x   = (const float*)d_in[0];
    const float* U1  = (const float*)d_in[1];
    const float* U2  = (const float*)d_in[2];
    const float* U3  = (const float*)d_in[3];
    const float* U4  = (const float*)d_in[4];
    const float* lam = (const float*)d_in[5];

    float* t3p = (float*)d_ws;                   // 128 * 32 * 64 * 4 B = 1 MB
    float* out = (float*)d_out;

    main_k<<<dim3(MM / 64, KSPLIT), 256, 0, stream>>>(x, U1, U2, U3, t3p);
    out_k<<<dim3(4, BB), 256, 0, stream>>>(t3p, lam, U4, out);
}